// Round 4
// baseline (586.916 us; speedup 1.0000x reference)
//
#include <hip/hip_runtime.h>
#include <hip/hip_bf16.h>

#define NN 10000
#define NE 640000
#define SD 128
#define HD1 60
#define HD2 30
#define CONCAT 10003
#define ACT 10000

typedef unsigned int u32;
typedef unsigned short u16;
typedef u16 u16x8 __attribute__((ext_vector_type(8)));
typedef float f32x4 __attribute__((ext_vector_type(4)));

__device__ __forceinline__ float bf2f_bits(u16 u) {
    return __uint_as_float(((u32)u) << 16);
}
__device__ __forceinline__ float loadF(const void* base, long idx, int bf) {
    if (bf) return bf2f_bits(((const u16*)base)[idx]);
    return ((const float*)base)[idx];
}
__device__ __forceinline__ int loadI(const void* base, long idx, int i64) {
    if (i64) return (int)((const long long*)base)[idx];
    return ((const int*)base)[idx];
}

// block 0 thread 0: detect dtypes -> flags[0]=edge-int64, flags[1]=floats-bf16.
// all blocks: zero deg[].
__global__ void k_probe_zero(const void* __restrict__ edge, const void* __restrict__ wa,
                             int* __restrict__ flags, int* __restrict__ deg) {
    int i = blockIdx.x * blockDim.x + threadIdx.x;
    if (i < NN) deg[i] = 0;
    if (i == 0) {
        const int* e32 = (const int*)edge;
        int i64like = 0;
        for (int e = 0; e < 64; ++e) {
            int lo = e32[2 * e], hi = e32[2 * e + 1];
            if (hi == 0 && lo >= 0 && lo < NN) i64like++;
        }
        flags[0] = (i64like >= 56) ? 1 : 0;
        const u32* w = (const u32*)wa;
        int cnt = 0;
        for (int j = 0; j < 256; ++j) {
            u32 lo = w[j] & 0xFFFFu;
            int ex = (int)((lo >> 7) & 0xFF);
            if (ex >= 100 && ex <= 140) cnt++;
        }
        flags[1] = (cnt >= 128) ? 1 : 0;
    }
}

__global__ void k_deg(const void* __restrict__ edge, const int* __restrict__ flags,
                      int* __restrict__ deg) {
    int e = blockIdx.x * blockDim.x + threadIdx.x;
    int i64f = flags[0];
    if (e < NE) atomicAdd(&deg[loadI(edge, NE + e, i64f)], 1);
}

// 1 block / 1024 threads: dinv + exclusive scan (10 elems/thread) + fill init.
__global__ void k_scan_fused(const int* __restrict__ deg, float* __restrict__ dinv,
                             int* __restrict__ row_ptr, int* __restrict__ fill) {
    __shared__ int part[1024];
    int tid = threadIdx.x;
    int base = tid * 10;
    int loc[10];
    int s = 0;
    for (int j = 0; j < 10; ++j) {
        int idx = base + j;
        int d = (idx < NN) ? deg[idx] : 0;
        loc[j] = s;
        s += d;
        if (idx < NN) dinv[idx] = d > 0 ? rsqrtf((float)d) : 0.f;
    }
    part[tid] = s;
    __syncthreads();
    for (int off = 1; off < 1024; off <<= 1) {
        int t = (tid >= off) ? part[tid - off] : 0;
        __syncthreads();
        part[tid] += t;
        __syncthreads();
    }
    int prefix = (tid > 0) ? part[tid - 1] : 0;
    for (int j = 0; j < 10; ++j) {
        int idx = base + j;
        if (idx < NN) {
            int r = prefix + loc[j];
            row_ptr[idx] = r;
            fill[idx] = r;
        }
    }
    if (tid == 1023) row_ptr[NN] = part[1023];
}

// csr record: .x = src col, .y = float bits of weight
__global__ void k_fill(const void* __restrict__ edge, const int* __restrict__ flags,
                       const float* __restrict__ dinv, int* __restrict__ fill,
                       int2* __restrict__ csr) {
    int e = blockIdx.x * blockDim.x + threadIdx.x;
    int i64f = flags[0];
    if (e < NE) {
        int s = loadI(edge, e, i64f);
        int d = loadI(edge, NE + e, i64f);
        int p = atomicAdd(&fill[d], 1);
        int2 rec;
        rec.x = s;
        rec.y = __float_as_int(-dinv[s] * dinv[d]);
        csr[p] = rec;
    }
}

// vectorized input -> f32 (8 elems/thread)
__global__ void k_loadx(const void* __restrict__ in, const int* __restrict__ flags,
                        float* __restrict__ out) {
    int i = blockIdx.x * blockDim.x + threadIdx.x;
    if (i >= NN * SD / 8) return;
    int bf = flags[1];
    float v[8];
    if (bf) {
        u16x8 u = ((const u16x8*)in)[i];
#pragma unroll
        for (int j = 0; j < 8; ++j) v[j] = bf2f_bits(u[j]);
    } else {
        f32x4 a = ((const f32x4*)in)[2 * i];
        f32x4 b = ((const f32x4*)in)[2 * i + 1];
#pragma unroll
        for (int j = 0; j < 4; ++j) { v[j] = a[j]; v[4 + j] = b[j]; }
    }
    f32x4* o = (f32x4*)(out + 8 * i);
    o[0] = (f32x4){v[0], v[1], v[2], v[3]};
    o[1] = (f32x4){v[4], v[5], v[6], v[7]};
}

// transpose weights to f32 Wt[k][o][j]; W stored [k][j][o]
__global__ void k_wt(const void* __restrict__ W1, const void* __restrict__ W2,
                     const void* __restrict__ W3, const int* __restrict__ flags,
                     float* __restrict__ Wt1, float* __restrict__ Wt2,
                     float* __restrict__ Wt3) {
    int t = blockIdx.x * blockDim.x + threadIdx.x;
    int bf = flags[1];
    if (t < 3 * SD * HD1) {
        int k = t / (SD * HD1), r = t % (SD * HD1);
        int j = r / HD1, o = r % HD1;
        Wt1[(k * HD1 + o) * SD + j] = loadF(W1, t, bf);
    } else if (t < 3 * SD * HD1 + 3 * HD1 * HD2) {
        int t2 = t - 3 * SD * HD1;
        int k = t2 / (HD1 * HD2), r = t2 % (HD1 * HD2);
        int j = r / HD2, o = r % HD2;
        Wt2[(k * HD2 + o) * HD1 + j] = loadF(W2, t2, bf);
    } else if (t < 3 * SD * HD1 + 3 * HD1 * HD2 + 3 * HD2) {
        int t3 = t - 3 * SD * HD1 - 3 * HD1 * HD2;
        Wt3[t3] = loadF(W3, t3, bf);  // [k][j][o=1] already contiguous in j
    }
}

// ---- SpMV: wave per row (D=128: 2 waves per row, half-dims each) ----
template <bool T2MODE>
__global__ void k_spmv128(const int* __restrict__ row_ptr, const int2* __restrict__ csr,
                          const float* __restrict__ x, const float* __restrict__ sub,
                          float* __restrict__ y) {
    int wid = (blockIdx.x * blockDim.x + threadIdx.x) >> 6;
    int lane = threadIdx.x & 63;
    if (wid >= NN * 2) return;
    int i = wid >> 1;
    int dd = ((wid & 1) << 6) + lane;
    int beg = row_ptr[i], end = row_ptr[i + 1];
    float acc = 0.f;
    int p = beg;
    for (; p + 3 < end; p += 4) {
        int2 e0 = csr[p], e1 = csr[p + 1], e2 = csr[p + 2], e3 = csr[p + 3];
        float x0 = x[(long)e0.x * 128 + dd];
        float x1 = x[(long)e1.x * 128 + dd];
        float x2 = x[(long)e2.x * 128 + dd];
        float x3 = x[(long)e3.x * 128 + dd];
        acc += __int_as_float(e0.y) * x0 + __int_as_float(e1.y) * x1 +
               __int_as_float(e2.y) * x2 + __int_as_float(e3.y) * x3;
    }
    for (; p < end; ++p) {
        int2 e = csr[p];
        acc += __int_as_float(e.y) * x[(long)e.x * 128 + dd];
    }
    long oi = (long)i * 128 + dd;
    y[oi] = T2MODE ? 2.f * acc - sub[oi] : acc;
}

template <bool T2MODE>
__global__ void k_spmv60(const int* __restrict__ row_ptr, const int2* __restrict__ csr,
                         const float* __restrict__ x, const float* __restrict__ sub,
                         float* __restrict__ y) {
    int wid = (blockIdx.x * blockDim.x + threadIdx.x) >> 6;
    int lane = threadIdx.x & 63;
    if (wid >= NN) return;
    int i = wid;
    int beg = row_ptr[i], end = row_ptr[i + 1];
    float acc = 0.f;
    int p = beg;
    for (; p + 3 < end; p += 4) {
        int2 e0 = csr[p], e1 = csr[p + 1], e2 = csr[p + 2], e3 = csr[p + 3];
        float x0 = x[(long)e0.x * 60 + lane];
        float x1 = x[(long)e1.x * 60 + lane];
        float x2 = x[(long)e2.x * 60 + lane];
        float x3 = x[(long)e3.x * 60 + lane];
        acc += __int_as_float(e0.y) * x0 + __int_as_float(e1.y) * x1 +
               __int_as_float(e2.y) * x2 + __int_as_float(e3.y) * x3;
    }
    for (; p < end; ++p) {
        int2 e = csr[p];
        acc += __int_as_float(e.y) * x[(long)e.x * 60 + lane];
    }
    if (lane < 60) {
        long oi = (long)i * 60 + lane;
        y[oi] = T2MODE ? 2.f * acc - sub[oi] : acc;
    }
}

// D=30: half-waves process alternate edges, combine via shfl
template <bool T2MODE>
__global__ void k_spmv30(const int* __restrict__ row_ptr, const int2* __restrict__ csr,
                         const float* __restrict__ x, const float* __restrict__ sub,
                         float* __restrict__ y) {
    int wid = (blockIdx.x * blockDim.x + threadIdx.x) >> 6;
    int lane = threadIdx.x & 63;
    if (wid >= NN) return;
    int i = wid;
    int h = lane >> 5, l = lane & 31;
    int beg = row_ptr[i], end = row_ptr[i + 1];
    float acc = 0.f;
    for (int p = beg + h; p < end; p += 2) {
        int2 e = csr[p];
        acc += __int_as_float(e.y) * x[(long)e.x * 30 + l];
    }
    acc += __shfl_xor(acc, 32);
    if (lane < 30) {
        long oi = (long)i * 30 + lane;
        y[oi] = T2MODE ? 2.f * acc - sub[oi] : acc;
    }
}

// out[i,o] = tanh(b[o] + sum_j T0*Wt[0,o,:] + T1*Wt[1,o,:] + T2*Wt[2,o,:])
template <int DIN, int DOUT, bool TAIL>
__global__ void k_cheb(const float* __restrict__ T0, const float* __restrict__ T1,
                       const float* __restrict__ T2, const float* __restrict__ Wt,
                       const void* __restrict__ b, const int* __restrict__ flags,
                       float* __restrict__ out, const void* s0, const void* s1,
                       const void* s2) {
    int t = blockIdx.x * blockDim.x + threadIdx.x;
    int bf = flags[1];
    if (TAIL && t == 0) {
        out[10000] = loadF(s0, 0, bf);
        out[10001] = loadF(s1, 0, bf);
        out[10002] = loadF(s2, 0, bf);
    }
    if (t >= NN * DOUT) return;
    int i = t / DOUT, o = t % DOUT;
    float acc = loadF(b, o, bf);
    if constexpr (DIN % 4 == 0) {
        const f32x4* t0 = (const f32x4*)(T0 + (long)i * DIN);
        const f32x4* t1 = (const f32x4*)(T1 + (long)i * DIN);
        const f32x4* t2 = (const f32x4*)(T2 + (long)i * DIN);
        const f32x4* w0 = (const f32x4*)(Wt + (0 * DOUT + o) * DIN);
        const f32x4* w1 = (const f32x4*)(Wt + (1 * DOUT + o) * DIN);
        const f32x4* w2 = (const f32x4*)(Wt + (2 * DOUT + o) * DIN);
#pragma unroll 4
        for (int j = 0; j < DIN / 4; ++j) {
            f32x4 a0 = t0[j], a1 = t1[j], a2 = t2[j];
            f32x4 b0 = w0[j], b1 = w1[j], b2 = w2[j];
#pragma unroll
            for (int q = 0; q < 4; ++q)
                acc += a0[q] * b0[q] + a1[q] * b1[q] + a2[q] * b2[q];
        }
    } else {
        const float* t0 = T0 + (long)i * DIN;
        const float* t1 = T1 + (long)i * DIN;
        const float* t2 = T2 + (long)i * DIN;
        for (int j = 0; j < DIN; ++j) {
            acc += t0[j] * Wt[0 * DOUT * DIN + o * DIN + j] +
                   t1[j] * Wt[1 * DOUT * DIN + o * DIN + j] +
                   t2[j] * Wt[2 * DOUT * DIN + o * DIN + j];
        }
    }
    out[t] = tanhf(acc);
}

// one wave per output row; vectorized 16B weight loads with alignment prologue.
__global__ void k_heads(const float* __restrict__ state, const void* __restrict__ Wa,
                        const void* __restrict__ ba, const void* __restrict__ Wc,
                        const void* __restrict__ bc, const int* __restrict__ flags,
                        void* __restrict__ out) {
    int wid = (blockIdx.x * blockDim.x + threadIdx.x) >> 6;
    int lane = threadIdx.x & 63;
    if (wid > ACT) return;
    int bf = flags[1];
    int row = wid;
    long base = (row < ACT) ? (long)row * CONCAT : 0;
    const void* wb = (row < ACT) ? Wa : Wc;
    float acc = 0.f;
    if (bf) {
        const u16* w = (const u16*)wb + base;
        int k = (int)((16 - ((2 * base) & 15)) & 15) >> 1;
        for (int i = lane; i < k; i += 64) acc += state[i] * bf2f_bits(w[i]);
        int nv = (CONCAT - k) >> 3;
        const u16x8* wv = (const u16x8*)(w + k);
        for (int v = lane; v < nv; v += 64) {
            u16x8 ww = wv[v];
            int ib = k + v * 8;
#pragma unroll
            for (int j = 0; j < 8; ++j) acc += state[ib + j] * bf2f_bits(ww[j]);
        }
        for (int i = k + nv * 8 + lane; i < CONCAT; i += 64)
            acc += state[i] * bf2f_bits(w[i]);
    } else {
        const float* w = (const float*)wb + base;
        int k = (int)((16 - ((4 * base) & 15)) & 15) >> 2;
        for (int i = lane; i < k; i += 64) acc += state[i] * w[i];
        int nv = (CONCAT - k) >> 2;
        const f32x4* wv = (const f32x4*)(w + k);
        for (int v = lane; v < nv; v += 64) {
            f32x4 ww = wv[v];
            int ib = k + v * 4;
#pragma unroll
            for (int j = 0; j < 4; ++j) acc += state[ib + j] * ww[j];
        }
        for (int i = k + nv * 4 + lane; i < CONCAT; i += 64)
            acc += state[i] * w[i];
    }
#pragma unroll
    for (int o = 32; o > 0; o >>= 1) acc += __shfl_xor(acc, o);
    if (lane == 0) {
        float bias = (row < ACT) ? loadF(ba, row, bf) : loadF(bc, 0, bf);
        float v = acc + bias;
        if (bf) ((__hip_bfloat16*)out)[row] = __float2bfloat16(v);
        else ((float*)out)[row] = v;
    }
}

extern "C" void kernel_launch(void* const* d_in, const int* in_sizes, int n_in,
                              void* d_out, int out_size, void* d_ws, size_t ws_size,
                              hipStream_t stream) {
    const void* x_in = d_in[0];
    const void* edge = d_in[1];
    const void* sc0 = d_in[2];
    const void* sc1 = d_in[3];
    const void* sc2 = d_in[4];
    const void* W1 = d_in[5];
    const void* b1 = d_in[6];
    const void* W2 = d_in[7];
    const void* b2 = d_in[8];
    const void* W3 = d_in[9];
    const void* b3 = d_in[10];
    const void* Wa = d_in[11];
    const void* ba = d_in[12];
    const void* Wc = d_in[13];
    const void* bc = d_in[14];

    char* p = (char*)d_ws;
    auto alloc = [&](size_t bytes) {
        char* r = p;
        p += (bytes + 255) & ~(size_t)255;
        return (void*)r;
    };
    int* flags = (int*)alloc(2 * 4);
    int* deg = (int*)alloc(NN * 4);
    float* dinv = (float*)alloc(NN * 4);
    int* row_ptr = (int*)alloc((NN + 1) * 4);
    int* fill = (int*)alloc(NN * 4);
    int2* csr = (int2*)alloc((size_t)NE * 8);
    float* X0 = (float*)alloc((size_t)NN * SD * 4);
    float* T1 = (float*)alloc((size_t)NN * SD * 4);
    float* T2 = (float*)alloc((size_t)NN * SD * 4);
    float* H1f = (float*)alloc((size_t)NN * HD1 * 4);
    float* H2f = (float*)alloc((size_t)NN * HD2 * 4);
    float* state = (float*)alloc(CONCAT * 4);
    float* Wt1 = (float*)alloc(3 * SD * HD1 * 4);
    float* Wt2 = (float*)alloc(3 * HD1 * HD2 * 4);
    float* Wt3 = (float*)alloc(3 * HD2 * 4);

    const int B = 256;
    k_probe_zero<<<(NN + B - 1) / B, B, 0, stream>>>(edge, Wa, flags, deg);
    k_deg<<<(NE + B - 1) / B, B, 0, stream>>>(edge, flags, deg);
    k_scan_fused<<<1, 1024, 0, stream>>>(deg, dinv, row_ptr, fill);
    k_fill<<<(NE + B - 1) / B, B, 0, stream>>>(edge, flags, dinv, fill, csr);
    k_loadx<<<(NN * SD / 8 + B - 1) / B, B, 0, stream>>>(x_in, flags, X0);
    int wt_n = 3 * SD * HD1 + 3 * HD1 * HD2 + 3 * HD2;
    k_wt<<<(wt_n + B - 1) / B, B, 0, stream>>>(W1, W2, W3, flags, Wt1, Wt2, Wt3);

    // layer 1: 128 -> 60 (2 waves per row)
    k_spmv128<false><<<(NN * 2 * 64 + B - 1) / B, B, 0, stream>>>(row_ptr, csr, X0, nullptr, T1);
    k_spmv128<true><<<(NN * 2 * 64 + B - 1) / B, B, 0, stream>>>(row_ptr, csr, T1, X0, T2);
    k_cheb<SD, HD1, false><<<(NN * HD1 + B - 1) / B, B, 0, stream>>>(X0, T1, T2, Wt1, b1, flags, H1f, nullptr, nullptr, nullptr);

    // layer 2: 60 -> 30 (1 wave per row)
    k_spmv60<false><<<(NN * 64 + B - 1) / B, B, 0, stream>>>(row_ptr, csr, H1f, nullptr, T1);
    k_spmv60<true><<<(NN * 64 + B - 1) / B, B, 0, stream>>>(row_ptr, csr, T1, H1f, T2);
    k_cheb<HD1, HD2, false><<<(NN * HD2 + B - 1) / B, B, 0, stream>>>(H1f, T1, T2, Wt2, b2, flags, H2f, nullptr, nullptr, nullptr);

    // layer 3: 30 -> 1 (+ tail scalars into state)
    k_spmv30<false><<<(NN * 64 + B - 1) / B, B, 0, stream>>>(row_ptr, csr, H2f, nullptr, T1);
    k_spmv30<true><<<(NN * 64 + B - 1) / B, B, 0, stream>>>(row_ptr, csr, T1, H2f, T2);
    k_cheb<HD2, 1, true><<<(NN + B - 1) / B, B, 0, stream>>>(H2f, T1, T2, Wt3, b3, flags, state, sc0, sc1, sc2);

    // heads: one wave per row, 10001 rows
    k_heads<<<((ACT + 1) * 64 + B - 1) / B, B, 0, stream>>>(state, Wa, ba, Wc, bc, flags, d_out);
}